// Round 25
// baseline (199.161 us; speedup 1.0000x reference)
//
#include <hip/hip_runtime.h>

#define D 256
#define H 8
#define DK 32
#define FF 1024
#define SEQ 2048
#define BATCH 4
#define MROWS (BATCH * SEQ)   // 8192
#define LN_EPS 1e-5f
#define QSCALE (0.1767766952966369f * 1.4426950408889634f)  // attn scale * log2(e)
#define LOG2E 1.4426950408889634f

typedef unsigned short u16;
typedef unsigned int u32;
typedef __attribute__((ext_vector_type(8))) short bf16x8;
typedef __attribute__((ext_vector_type(4))) float f32x4;

#define MFMA16(a, b, c) __builtin_amdgcn_mfma_f32_16x16x32_bf16(a, b, c, 0, 0, 0)

#if __has_builtin(__builtin_amdgcn_exp2f)
#define EXP2(x) __builtin_amdgcn_exp2f(x)
#else
#define EXP2(x) exp2f(x)
#endif
#if __has_builtin(__builtin_amdgcn_rcpf)
#define RCPF(x) __builtin_amdgcn_rcpf(x)
#else
#define RCPF(x) (1.f / (x))
#endif

// ---------- bf16 helpers ----------
__device__ __forceinline__ u16 f2bf(float f) {
    union { float f; u32 u; } x; x.f = f;
    u32 r = x.u + 0x7fffu + ((x.u >> 16) & 1u);  // RNE
    return (u16)(r >> 16);
}
__device__ __forceinline__ u32 pack2(float a, float b) {
    return (u32)f2bf(a) | ((u32)f2bf(b) << 16);
}
__device__ __forceinline__ u32 pktrunc(float a, float b) {
    u32 ua = __builtin_bit_cast(u32, a), ub = __builtin_bit_cast(u32, b);
    return __builtin_amdgcn_perm(ub, ua, 0x07060302u);
}
__device__ __forceinline__ float silu_f(float x) {
    return x * RCPF(1.f + EXP2(-x * LOG2E));
}

// ---------- stage all 7 weights: f32 [K,N] -> bf16 [N,K], LDS-tiled ----------
__global__ void stage_w(const float* __restrict__ Wq, const float* __restrict__ Wk,
                        const float* __restrict__ Wv, const float* __restrict__ Wo,
                        const float* __restrict__ W1, const float* __restrict__ W2,
                        const float* __restrict__ Wout, u16* __restrict__ dst) {
    __shared__ float T[64][65];
    int bid = blockIdx.x, tid = threadIdx.x;
    const float* src;
    size_t dbase;
    int K, N, tile;
    float sc = 1.f;
    if (bid < 64) {
        int which = bid >> 4;
        tile = bid & 15;
        src = which == 0 ? Wq : which == 1 ? Wk : which == 2 ? Wv : Wo;
        if (which == 0) sc = QSCALE;
        dbase = (size_t)which << 16;
        K = 256; N = 256;
    } else if (bid < 192) {
        int which = (bid - 64) >> 6;
        tile = (bid - 64) & 63;
        src = which ? W2 : W1;
        dbase = 262144 + (size_t)which * 262144;
        K = 256; N = 1024;
    } else {
        tile = bid - 192;
        src = Wout;
        dbase = 786432;
        K = 1024; N = 256;
    }
    int ntn = N >> 6;
    int k0 = (tile / ntn) << 6, n0 = (tile % ntn) << 6;
#pragma unroll
    for (int p = 0; p < 4; p++) {
        int r = p * 16 + (tid >> 4), c = (tid & 15) * 4;
        float4 v = *(const float4*)(src + (size_t)(k0 + r) * N + n0 + c);
        T[c + 0][r] = v.x * sc;
        T[c + 1][r] = v.y * sc;
        T[c + 2][r] = v.z * sc;
        T[c + 3][r] = v.w * sc;
    }
    __syncthreads();
#pragma unroll
    for (int p = 0; p < 4; p++) {
        int n = p * 16 + (tid >> 4), k = (tid & 15) * 4;
        uint2 o;
        o.x = pack2(T[n][k], T[n][k + 1]);
        o.y = pack2(T[n][k + 2], T[n][k + 3]);
        *(uint2*)(dst + dbase + (size_t)(n0 + n) * K + k0 + k) = o;
    }
}

// ---------- weight-stationary QKV GEMM (R24) ----------
__global__ __launch_bounds__(512, 3)
void gemm_qkv(const float* __restrict__ X, const u16* __restrict__ Bt,
              u16* __restrict__ Qo, u16* __restrict__ Ko,
              u16* __restrict__ Vo) {
    __shared__ __align__(16) u16 WL[64][260];
    int tid = threadIdx.x;
    int w = tid >> 6, lane = tid & 63;
    int m = lane & 15, quad = lane >> 4;
    int cg = blockIdx.x % 12, rg = blockIdx.x / 12;
    int n0 = cg << 6;
#pragma unroll
    for (int i = 0; i < 4; i++) {
        int idx = i * 512 + tid;
        int row = idx >> 5, seg = idx & 31;
        *(uint4*)(&WL[row][seg * 8]) =
            *(const uint4*)(Bt + (size_t)(n0 + row) * D + seg * 8);
    }
    __syncthreads();
    int m0 = rg * 128 + w * 16;            // this wave's 16 rows
    const float* xp = X + (size_t)(m0 + m) * D + quad * 8;
    f32x4 acc[4] = {{0,0,0,0},{0,0,0,0},{0,0,0,0},{0,0,0,0}};
#pragma unroll
    for (int k0 = 0; k0 < D; k0 += 32) {
        float4 f0 = *(const float4*)(xp + k0);
        float4 f1 = *(const float4*)(xp + k0 + 4);
        uint4 u0;
        u0.x = pktrunc(f0.x, f0.y); u0.y = pktrunc(f0.z, f0.w);
        u0.z = pktrunc(f1.x, f1.y); u0.w = pktrunc(f1.z, f1.w);
        bf16x8 a0 = __builtin_bit_cast(bf16x8, u0);
#pragma unroll
        for (int t = 0; t < 4; t++) {
            bf16x8 bv = *(const bf16x8*)(&WL[t * 16 + m][k0 + quad * 8]);
            acc[t] = MFMA16(a0, bv, acc[t]);
        }
    }
    int seg = cg >> 2;
    int nc0 = (cg & 3) << 6;
    int row = m0 + (quad << 2);
    if (seg < 2) {
        u16* out = seg ? Ko : Qo;
#pragma unroll
        for (int t = 0; t < 4; t++) {
            int col = nc0 + t * 16 + m;
#pragma unroll
            for (int r = 0; r < 4; r++)
                out[(size_t)(row + r) * D + col] = f2bf(acc[t][r]);
        }
    } else {
        int b = row >> 11, sl = row & 2047;
#pragma unroll
        for (int t = 0; t < 4; t++) {
            int col = nc0 + t * 16 + m;          // d in [0,256)
            int hh = col >> 5, dk = col & 31;
            size_t base = ((size_t)(b * 8 + hh) * 32 + dk) * SEQ + sl;
            uint2 pk;
            pk.x = pack2(acc[t][0], acc[t][1]);
            pk.y = pack2(acc[t][2], acc[t][3]);
            *(uint2*)(Vo + base) = pk;
        }
    }
}

// ---------- MFMA flash attention: 64 q-rows/block, kv-split waves ----------
// 1024 blocks = 32 heads x 32 q-blocks of 64 rows; 4 waves.
// Wave (w&1) -> q half (32 rows, 2 B-frags); (w>>1) -> kv half (2 score tiles).
// K/V traffic per CU halves vs 32-row blocks. No-max softmax, raw v_exp.
__global__ __launch_bounds__(256, 8)
void attn_mfma(const u16* __restrict__ Q, const u16* __restrict__ Km,
               const u16* __restrict__ Vt, u16* __restrict__ O) {
    __shared__ __align__(16) u16 Kt[2][64][36];
    __shared__ __align__(16) u16 Vl[2][32][68];
    int tid = threadIdx.x;
    int lane = tid & 63;
    int m = lane & 15, quad = lane >> 4;
    int w = tid >> 6;
    int bid = blockIdx.x;
    int qb = bid & 31;          // 32 q-blocks of 64 rows
    int bh = bid >> 5;          // b*8+h
    int b = bh >> 3, h = bh & 7;
    int q0 = qb * 64 + (w & 1) * 32;
    int hb = w >> 1;            // kv half: score tiles 2hb, 2hb+1
    size_t rowbase = (size_t)b * SEQ;

    bf16x8 qa0 = *(const bf16x8*)(Q + (rowbase + q0 + m) * D + h * DK + quad * 8);
    bf16x8 qa1 = *(const bf16x8*)(Q + (rowbase + q0 + 16 + m) * D + h * DK + quad * 8);

    const u16* kg = Km + rowbase * D + h * DK;
    const u16* vg = Vt + (size_t)bh * DK * SEQ;

    int krow = tid >> 2, kseg = tid & 3;
    int skv = (krow & 32) | (((krow >> 2) & 3) << 3) | (((krow >> 4) & 1) << 2) | (krow & 3);
    int vrow = tid >> 3, vseg = tid & 7;

    uint4 kreg = *(const uint4*)(kg + (size_t)skv * D + kseg * 8);
    uint4 vreg = *(const uint4*)(vg + (size_t)vrow * SEQ + vseg * 8);
    *(uint4*)(&Kt[0][krow][kseg * 8]) = kreg;
    *(uint4*)(&Vl[0][vrow][vseg * 8]) = vreg;

    f32x4 o0 = {0,0,0,0}, o1 = {0,0,0,0};   // q rows q0..q0+16
    f32x4 o2 = {0,0,0,0}, o3 = {0,0,0,0};   // q rows q0+16..q0+32
    float ls0 = 0.f, ls1 = 0.f;

    for (int i = 0; i < SEQ / 64; i++) {
        int buf = i & 1;
        if (i + 1 < SEQ / 64) {
            int kvn = (i + 1) * 64;
            kreg = *(const uint4*)(kg + (size_t)(kvn + skv) * D + kseg * 8);
            vreg = *(const uint4*)(vg + (size_t)vrow * SEQ + kvn + vseg * 8);
        }
        __syncthreads();
        f32x4 z = {0,0,0,0};
        bf16x8 kb0 = *(const bf16x8*)(&Kt[buf][(2 * hb) * 16 + m][quad * 8]);
        bf16x8 kb1 = *(const bf16x8*)(&Kt[buf][(2 * hb + 1) * 16 + m][quad * 8]);
        f32x4 s0 = MFMA16(kb0, qa0, z);
        f32x4 s1 = MFMA16(kb1, qa0, z);
        f32x4 s2 = MFMA16(kb0, qa1, z);
        f32x4 s3 = MFMA16(kb1, qa1, z);
        bf16x8 vb0 = *(const bf16x8*)(&Vl[buf][m][hb * 32 + quad * 8]);
        bf16x8 vb1 = *(const bf16x8*)(&Vl[buf][16 + m][hb * 32 + quad * 8]);
        {
            float pa0 = EXP2(s0[0]), pa1 = EXP2(s0[1]);
            float pa2 = EXP2(s0[2]), pa3 = EXP2(s0[3]);
            float pb0 = EXP2(s1[0]), pb1 = EXP2(s1[1]);
            float pb2 = EXP2(s1[2]), pb3 = EXP2(s1[3]);
            ls0 += ((pa0 + pa1) + (pa2 + pa3)) + ((pb0 + pb1) + (pb2 + pb3));
            uint4 pw;
            pw.x = pktrunc(pa0, pa1);
            pw.y = pktrunc(pa2, pa3);
            pw.z = pktrunc(pb0, pb1);
            pw.w = pktrunc(pb2, pb3);
            bf16x8 pf = __builtin_bit_cast(bf16x8, pw);
            o0 = MFMA16(pf, vb0, o0);
            o1 = MFMA16(pf, vb1, o1);
        }
        {
            float pa0 = EXP2(s2[0]), pa1 = EXP2(s2[1]);
            float pa2 = EXP2(s2[2]), pa3 = EXP2(s2[3]);
            float pb0 = EXP2(s3[0]), pb1 = EXP2(s3[1]);
            float pb2 = EXP2(s3[2]), pb3 = EXP2(s3[3]);
            ls1 += ((pa0 + pa1) + (pa2 + pa3)) + ((pb0 + pb1) + (pb2 + pb3));
            uint4 pw;
            pw.x = pktrunc(pa0, pa1);
            pw.y = pktrunc(pa2, pa3);
            pw.z = pktrunc(pb0, pb1);
            pw.w = pktrunc(pb2, pb3);
            bf16x8 pf = __builtin_bit_cast(bf16x8, pw);
            o2 = MFMA16(pf, vb0, o2);
            o3 = MFMA16(pf, vb1, o3);
        }
        if (i + 1 < SEQ / 64) {
            *(uint4*)(&Kt[buf ^ 1][krow][kseg * 8]) = kreg;
            *(uint4*)(&Vl[buf ^ 1][vrow][vseg * 8]) = vreg;
        }
    }
    // reduce ls across quads (q = m), then combine kv halves through LDS
    ls0 += __shfl_xor(ls0, 16); ls0 += __shfl_xor(ls0, 32);
    ls1 += __shfl_xor(ls1, 16); ls1 += __shfl_xor(ls1, 32);
    __syncthreads();                        // everyone done with Kt/Vl
    float* comb = (float*)&Kt[0][0][0];     // 2 slots x 64 lanes x 18 floats = 9216 B
    if (w >= 2) {
        float* c = comb + ((size_t)(w - 2) * 64 + lane) * 18;
#pragma unroll
        for (int r = 0; r < 4; r++) {
            c[r] = o0[r]; c[4 + r] = o1[r];
            c[8 + r] = o2[r]; c[12 + r] = o3[r];
        }
        c[16] = ls0; c[17] = ls1;
    }
    __syncthreads();
    if (w < 2) {
        const float* c = comb + ((size_t)w * 64 + lane) * 18;
#pragma unroll
        for (int r = 0; r < 4; r++) {
            o0[r] += c[r]; o1[r] += c[4 + r];
            o2[r] += c[8 + r]; o3[r] += c[12 + r];
        }
        ls0 += c[16]; ls1 += c[17];
        u16* ob0 = O + (rowbase + q0 + quad * 4) * D + h * DK;
        u16* ob1 = O + (rowbase + q0 + 16 + quad * 4) * D + h * DK;
#pragma unroll
        for (int r = 0; r < 4; r++) {
            float l0 = __shfl(ls0, quad * 4 + r);
            float l1 = __shfl(ls1, quad * 4 + r);
            float i0 = 1.f / l0, i1 = 1.f / l1;
            ob0[(size_t)r * D + m] = f2bf(o0[r] * i0);
            ob0[(size_t)r * D + 16 + m] = f2bf(o1[r] * i0);
            ob1[(size_t)r * D + m] = f2bf(o2[r] * i1);
            ob1[(size_t)r * D + 16 + m] = f2bf(o3[r] * i1);
        }
    }
}

// ---------- Wo GEMM + residual + LN -> f32 x1 + bf16 x1 (16-row blocks) ----------
__global__ __launch_bounds__(256, 2)
void wo_res_ln(const u16* __restrict__ A, const u16* __restrict__ Bt,
               const float* __restrict__ res, const float* __restrict__ g,
               const float* __restrict__ bb, float* __restrict__ outf,
               u16* __restrict__ outb) {
    __shared__ float Sy[4][16], Sq[4][16], Mu[16], Rs[16];
    int tid = threadIdx.x;
    int w = tid >> 6, lane = tid & 63;
    int m = lane & 15, quad = lane >> 4;
    int m0 = blockIdx.x << 4, n0 = w << 6;
    const u16* ap = A + (size_t)(m0 + m) * D + quad * 8;
    const u16* bp = Bt + (size_t)(n0 + m) * D + quad * 8;
    f32x4 acc[4] = {{0,0,0,0},{0,0,0,0},{0,0,0,0},{0,0,0,0}};
#pragma unroll
    for (int k0 = 0; k0 < D; k0 += 32) {
        bf16x8 a0 = *(const bf16x8*)(ap + k0);
#pragma unroll
        for (int t = 0; t < 4; t++)
            acc[t] = MFMA16(a0, *(const bf16x8*)(bp + (size_t)t * 16 * D + k0), acc[t]);
    }
#pragma unroll
    for (int r = 0; r < 4; r++) {
        int row = (quad << 2) + r;
        float sy = 0.f, sq = 0.f;
#pragma unroll
        for (int t = 0; t < 4; t++) {
            float y = acc[t][r] + res[(size_t)(m0 + row) * D + n0 + t * 16 + m];
            acc[t][r] = y;
            sy += y;
            sq += y * y;
        }
        sy += __shfl_xor(sy, 1); sq += __shfl_xor(sq, 1);
        sy += __shfl_xor(sy, 2); sq += __shfl_xor(sq, 2);
        sy += __shfl_xor(sy, 4); sq += __shfl_xor(sq, 4);
        sy += __shfl_xor(sy, 8); sq += __shfl_xor(sq, 8);
        if (m == 0) { Sy[w][row] = sy; Sq[w][row] = sq; }
    }
    __syncthreads();
    if (tid < 16) {
        float s = Sy[0][tid] + Sy[1][tid] + Sy[2][tid] + Sy[3][tid];
        float q = Sq[0][tid] + Sq[1][tid] + Sq[2][tid] + Sq[3][tid];
        float mu = s * (1.f / 256.f);
        float var = q * (1.f / 256.f) - mu * mu;
        Mu[tid] = mu;
        Rs[tid] = rsqrtf(var + LN_EPS);
    }
    __syncthreads();
#pragma unroll
    for (int r = 0; r < 4; r++) {
        int row = (quad << 2) + r;
        float mu = Mu[row], rs = Rs[row];
#pragma unroll
        for (int t = 0; t < 4; t++) {
            int col = n0 + t * 16 + m;
            float yv = (acc[t][r] - mu) * rs * g[col] + bb[col];
            outf[(size_t)(m0 + row) * D + col] = yv;
            outb[(size_t)(m0 + row) * D + col] = f2bf(yv);
        }
    }
}

// ---------- weight-stationary GLU: block owns 64 FF cols x 512 rows ----------
__global__ __launch_bounds__(512, 2)
void glu_ws(const u16* __restrict__ x1b, const u16* __restrict__ W1t,
            const u16* __restrict__ W2t, u16* __restrict__ G) {
    __shared__ __align__(16) u16 WL[2][64][260];
    int tid = threadIdx.x;
    int w = tid >> 6, lane = tid & 63;
    int m = lane & 15, quad = lane >> 4;
    int cg = blockIdx.x & 15, rg = blockIdx.x >> 4;
    int n0 = cg << 6;
#pragma unroll
    for (int i = 0; i < 4; i++) {
        int idx = i * 512 + tid;           // [0, 2048)
        int row = idx >> 5, seg = idx & 31;
        *(uint4*)(&WL[0][row][seg * 8]) =
            *(const uint4*)(W1t + (size_t)(n0 + row) * D + seg * 8);
        *(uint4*)(&WL[1][row][seg * 8]) =
            *(const uint4*)(W2t + (size_t)(n0 + row) * D + seg * 8);
    }
    __syncthreads();
    int mr = rg * 512 + w * 64;            // this wave's 64 rows
    f32x4 a1[4][4], a2[4][4];
#pragma unroll
    for (int u = 0; u < 4; u++)
#pragma unroll
        for (int t = 0; t < 4; t++) {
            a1[u][t] = (f32x4){0.f, 0.f, 0.f, 0.f};
            a2[u][t] = (f32x4){0.f, 0.f, 0.f, 0.f};
        }
#pragma unroll
    for (int k0 = 0; k0 < D; k0 += 32) {
        bf16x8 av[4];
#pragma unroll
        for (int u = 0; u < 4; u++)
            av[u] = *(const bf16x8*)(x1b + (size_t)(mr + u * 16 + m) * D + k0 + quad * 8);
#pragma unroll
        for (int t = 0; t < 4; t++) {
            bf16x8 w1 = *(const bf16x8*)(&WL[0][t * 16 + m][k0 + quad * 8]);
            bf16x8 w2 = *(const bf16x8*)(&WL[1][t * 16 + m][k0 + quad * 8]);
#pragma unroll
            for (int u = 0; u < 4; u++) {
                a1[u][t] = MFMA16(av[u], w1, a1[u][t]);
                a2[u][t] = MFMA16(av[u], w2, a2[u][t]);
            }
        }
    }
#pragma unroll
    for (int u = 0; u < 4; u++) {
        int row = mr + u * 16 + (quad << 2);
#pragma unroll
        for (int t = 0; t < 4; t++) {
            int col = n0 + t * 16 + m;
#pragma unroll
            for (int r = 0; r < 4; r++)
                G[(size_t)(row + r) * FF + col] = f2bf(silu_f(a1[u][t][r]) * a2[u][t][r]);
        }
    }
}

// ---------- Wout GEMM + residual + LN -> f32 d_out ----------
__global__ __launch_bounds__(1024, 4)
void wout_ln(const u16* __restrict__ G, const u16* __restrict__ Woutt,
             const float* __restrict__ x1f, const float* __restrict__ g,
             const float* __restrict__ bb, float* __restrict__ outf) {
    __shared__ __align__(16) u16 Gl[32][1044];
    __shared__ float Sy[16][32], Sq[16][32], Mu[32], Rs[32];
    int tid = threadIdx.x;
    int w = tid >> 6, lane = tid & 63;
    int m = lane & 15, quad = lane >> 4;
    int m0 = blockIdx.x << 5;
#pragma unroll
    for (int i = 0; i < 4; i++) {
        int idx = i * 1024 + tid;          // [0, 4096)
        int row = idx >> 7, seg = idx & 127;
        *(uint4*)(&Gl[row][seg * 8]) =
            *(const uint4*)(G + (size_t)(m0 + row) * FF + seg * 8);
    }
    __syncthreads();
    int n0p = w << 4;
    const u16* bp = Woutt + (size_t)(n0p + m) * FF + quad * 8;
    f32x4 acc[2] = {{0,0,0,0},{0,0,0,0}};
#pragma unroll 4
    for (int k0 = 0; k0 < FF; k0 += 32) {
        bf16x8 a0 = *(const bf16x8*)(&Gl[m][k0 + quad * 8]);
        bf16x8 a1v = *(const bf16x8*)(&Gl[16 + m][k0 + quad * 8]);
        bf16x8 bv = *(const bf16x8*)(bp + k0);
        acc[0] = MFMA16(a0, bv, acc[0]);
        acc[1] = MFMA16(a1v, bv, acc[1]);
    }
#pragma unroll
    for (int u = 0; u < 2; u++) {
#pragma unroll
        for (int r = 0; r < 4; r++) {
            int row = u * 16 + (quad << 2) + r;
            float y = acc[u][r] + x1f[(size_t)(m0 + row) * D + n0p + m];
            acc[u][r] = y;
            float sy = y, sq = y * y;
            sy += __shfl_xor(sy, 1); sq += __shfl_xor(sq, 1);
            sy += __shfl_xor(sy, 2); sq += __shfl_xor(sq, 2);
            sy += __shfl_xor(sy, 4); sq += __shfl_xor(sq, 4);
            sy += __shfl_xor(sy, 8); sq += __shfl_xor(sq, 8);
            if (m == 0) { Sy[w][row] = sy; Sq[w][row] = sq; }
        }
    }
    __syncthreads();
    if (tid < 32) {
        float s = 0.f, q = 0.f;
#pragma unroll
        for (int ww = 0; ww < 16; ww++) { s += Sy[ww][tid]; q += Sq[ww][tid]; }
        float mu = s * (1.f / 256.f);
        float var = q * (1.f / 256.f) - mu * mu;
        Mu[tid] = mu;
        Rs[tid] = rsqrtf(var + LN_EPS);
    }
    __syncthreads();
#pragma unroll
    for (int u = 0; u < 2; u++) {
#pragma unroll
        for (int r = 0; r < 4; r++) {
            int row = u * 16 + (quad << 2) + r;
            int col = n0p + m;
            outf[(size_t)(m0 + row) * D + col] =
                (acc[u][r] - Mu[row]) * Rs[row] * g[col] + bb[col];
        }
    }
}

// ---------- workspace layout (u16 element offsets), ~31.5 MiB ----------
#define WS_WQKVT  ((size_t)0)          // WqT|WkT|WvT|WoT, 65536 each
#define WS_WOT    ((size_t)196608)
#define WS_W1T    ((size_t)262144)
#define WS_W2T    ((size_t)524288)
#define WS_WOUTT  ((size_t)786432)
#define WS_Q      ((size_t)1048576)    // dead after attn
#define WS_K      ((size_t)3145728)    // dead after attn
#define WS_VT     ((size_t)5242880)    // dead after attn
#define WS_O      ((size_t)7340032)    // dead after wo_res_ln
#define WS_GATED  ((size_t)1048576)    // alias Q..O: exactly 8,388,608 elems
#define WS_X1F    ((size_t)9437184)    // f32 x1 (4,194,304 u16-equiv)
#define WS_X1B    ((size_t)13631488)   // bf16 x1 (2,097,152)
// end: 15,728,640 u16 = 31,457,280 bytes

extern "C" void kernel_launch(void* const* d_in, const int* in_sizes, int n_in,
                              void* d_out, int out_size, void* d_ws, size_t ws_size,
                              hipStream_t stream) {
    const float* x    = (const float*)d_in[0];
    const float* Wq   = (const float*)d_in[1];
    const float* Wk   = (const float*)d_in[2];
    const float* Wv   = (const float*)d_in[3];
    const float* Wo   = (const float*)d_in[4];
    const float* W1   = (const float*)d_in[5];
    const float* W2   = (const float*)d_in[6];
    const float* Wout = (const float*)d_in[7];
    const float* g1   = (const float*)d_in[8];
    const float* b1   = (const float*)d_in[9];
    const float* g2   = (const float*)d_in[10];
    const float* b2   = (const float*)d_in[11];

    u16* ws = (u16*)d_ws;
    float* x1f = (float*)(ws + WS_X1F);

    // 1. stage all weights (transposed bf16, Wq prescaled)
    stage_w<<<256, 256, 0, stream>>>(Wq, Wk, Wv, Wo, W1, W2, Wout, ws + WS_WQKVT);

    // 2. weight-stationary QKV projection from f32 x (V written transposed)
    gemm_qkv<<<768, 512, 0, stream>>>(x, ws + WS_WQKVT,
                                      ws + WS_Q, ws + WS_K, ws + WS_VT);

    // 3. MFMA flash attention (64 q-rows/block, kv-split waves)
    attn_mfma<<<1024, 256, 0, stream>>>(ws + WS_Q, ws + WS_K, ws + WS_VT, ws + WS_O);

    // 4. x1 = LN(x + O@Wo) -> f32 + bf16
    wo_res_ln<<<512, 256, 0, stream>>>(ws + WS_O, ws + WS_WOT, x, g1, b1,
                                       x1f, ws + WS_X1B);

    // 5. gated = silu(x1@W1)*(x1@W2)  (weight-stationary, 64 KB LDS weights)
    glu_ws<<<256, 512, 0, stream>>>(ws + WS_X1B, ws + WS_W1T, ws + WS_W2T,
                                    ws + WS_GATED);

    // 6. out = LN(x1 + gated@Wout) -> f32 d_out (gated tile fully in LDS)
    wout_ln<<<256, 1024, 0, stream>>>(ws + WS_GATED, ws + WS_WOUTT, x1f,
                                      g2, b2, (float*)d_out);
}

// Round 26
// 178.147 us; speedup vs baseline: 1.1180x; 1.1180x over previous
//
#include <hip/hip_runtime.h>

#define D 256
#define H 8
#define DK 32
#define FF 1024
#define SEQ 2048
#define BATCH 4
#define MROWS (BATCH * SEQ)   // 8192
#define LN_EPS 1e-5f
#define QSCALE (0.1767766952966369f * 1.4426950408889634f)  // attn scale * log2(e)
#define LOG2E 1.4426950408889634f

typedef unsigned short u16;
typedef unsigned int u32;
typedef __attribute__((ext_vector_type(8))) short bf16x8;
typedef __attribute__((ext_vector_type(4))) float f32x4;

#define MFMA16(a, b, c) __builtin_amdgcn_mfma_f32_16x16x32_bf16(a, b, c, 0, 0, 0)

#if __has_builtin(__builtin_amdgcn_exp2f)
#define EXP2(x) __builtin_amdgcn_exp2f(x)
#else
#define EXP2(x) exp2f(x)
#endif
#if __has_builtin(__builtin_amdgcn_rcpf)
#define RCPF(x) __builtin_amdgcn_rcpf(x)
#else
#define RCPF(x) (1.f / (x))
#endif

// ---------- bf16 helpers ----------
__device__ __forceinline__ u16 f2bf(float f) {
    union { float f; u32 u; } x; x.f = f;
    u32 r = x.u + 0x7fffu + ((x.u >> 16) & 1u);  // RNE
    return (u16)(r >> 16);
}
__device__ __forceinline__ u32 pack2(float a, float b) {
    return (u32)f2bf(a) | ((u32)f2bf(b) << 16);
}
__device__ __forceinline__ u32 pktrunc(float a, float b) {
    u32 ua = __builtin_bit_cast(u32, a), ub = __builtin_bit_cast(u32, b);
    return __builtin_amdgcn_perm(ub, ua, 0x07060302u);
}
__device__ __forceinline__ float silu_f(float x) {
    return x * RCPF(1.f + EXP2(-x * LOG2E));
}

// ---------- stage all 7 weights: f32 [K,N] -> bf16 [N,K], LDS-tiled ----------
__global__ void stage_w(const float* __restrict__ Wq, const float* __restrict__ Wk,
                        const float* __restrict__ Wv, const float* __restrict__ Wo,
                        const float* __restrict__ W1, const float* __restrict__ W2,
                        const float* __restrict__ Wout, u16* __restrict__ dst) {
    __shared__ float T[64][65];
    int bid = blockIdx.x, tid = threadIdx.x;
    const float* src;
    size_t dbase;
    int K, N, tile;
    float sc = 1.f;
    if (bid < 64) {
        int which = bid >> 4;
        tile = bid & 15;
        src = which == 0 ? Wq : which == 1 ? Wk : which == 2 ? Wv : Wo;
        if (which == 0) sc = QSCALE;
        dbase = (size_t)which << 16;
        K = 256; N = 256;
    } else if (bid < 192) {
        int which = (bid - 64) >> 6;
        tile = (bid - 64) & 63;
        src = which ? W2 : W1;
        dbase = 262144 + (size_t)which * 262144;
        K = 256; N = 1024;
    } else {
        tile = bid - 192;
        src = Wout;
        dbase = 786432;
        K = 1024; N = 256;
    }
    int ntn = N >> 6;
    int k0 = (tile / ntn) << 6, n0 = (tile % ntn) << 6;
#pragma unroll
    for (int p = 0; p < 4; p++) {
        int r = p * 16 + (tid >> 4), c = (tid & 15) * 4;
        float4 v = *(const float4*)(src + (size_t)(k0 + r) * N + n0 + c);
        T[c + 0][r] = v.x * sc;
        T[c + 1][r] = v.y * sc;
        T[c + 2][r] = v.z * sc;
        T[c + 3][r] = v.w * sc;
    }
    __syncthreads();
#pragma unroll
    for (int p = 0; p < 4; p++) {
        int n = p * 16 + (tid >> 4), k = (tid & 15) * 4;
        uint2 o;
        o.x = pack2(T[n][k], T[n][k + 1]);
        o.y = pack2(T[n][k + 2], T[n][k + 3]);
        *(uint2*)(dst + dbase + (size_t)(n0 + n) * K + k0 + k) = o;
    }
}

// ---------- weight-stationary QKV GEMM (R24) ----------
__global__ __launch_bounds__(512, 3)
void gemm_qkv(const float* __restrict__ X, const u16* __restrict__ Bt,
              u16* __restrict__ Qo, u16* __restrict__ Ko,
              u16* __restrict__ Vo) {
    __shared__ __align__(16) u16 WL[64][260];
    int tid = threadIdx.x;
    int w = tid >> 6, lane = tid & 63;
    int m = lane & 15, quad = lane >> 4;
    int cg = blockIdx.x % 12, rg = blockIdx.x / 12;
    int n0 = cg << 6;
#pragma unroll
    for (int i = 0; i < 4; i++) {
        int idx = i * 512 + tid;
        int row = idx >> 5, seg = idx & 31;
        *(uint4*)(&WL[row][seg * 8]) =
            *(const uint4*)(Bt + (size_t)(n0 + row) * D + seg * 8);
    }
    __syncthreads();
    int m0 = rg * 128 + w * 16;            // this wave's 16 rows
    const float* xp = X + (size_t)(m0 + m) * D + quad * 8;
    f32x4 acc[4] = {{0,0,0,0},{0,0,0,0},{0,0,0,0},{0,0,0,0}};
#pragma unroll
    for (int k0 = 0; k0 < D; k0 += 32) {
        float4 f0 = *(const float4*)(xp + k0);
        float4 f1 = *(const float4*)(xp + k0 + 4);
        uint4 u0;
        u0.x = pktrunc(f0.x, f0.y); u0.y = pktrunc(f0.z, f0.w);
        u0.z = pktrunc(f1.x, f1.y); u0.w = pktrunc(f1.z, f1.w);
        bf16x8 a0 = __builtin_bit_cast(bf16x8, u0);
#pragma unroll
        for (int t = 0; t < 4; t++) {
            bf16x8 bv = *(const bf16x8*)(&WL[t * 16 + m][k0 + quad * 8]);
            acc[t] = MFMA16(a0, bv, acc[t]);
        }
    }
    int seg = cg >> 2;
    int nc0 = (cg & 3) << 6;
    int row = m0 + (quad << 2);
    if (seg < 2) {
        u16* out = seg ? Ko : Qo;
#pragma unroll
        for (int t = 0; t < 4; t++) {
            int col = nc0 + t * 16 + m;
#pragma unroll
            for (int r = 0; r < 4; r++)
                out[(size_t)(row + r) * D + col] = f2bf(acc[t][r]);
        }
    } else {
        int b = row >> 11, sl = row & 2047;
#pragma unroll
        for (int t = 0; t < 4; t++) {
            int col = nc0 + t * 16 + m;          // d in [0,256)
            int hh = col >> 5, dk = col & 31;
            size_t base = ((size_t)(b * 8 + hh) * 32 + dk) * SEQ + sl;
            uint2 pk;
            pk.x = pack2(acc[t][0], acc[t][1]);
            pk.y = pack2(acc[t][2], acc[t][3]);
            *(uint2*)(Vo + base) = pk;
        }
    }
}

// ---------- MFMA flash attention: 64 q-rows/block, kv-split waves ----------
// 1024 blocks = 32 heads x 32 q-blocks of 64 rows; 4 waves.
// launch_bounds(256,4): 128-VGPR budget so the doubled accumulator state
// (4 acc + 2 Q-frags + prefetch) does NOT spill (R25's (256,8) spilled).
__global__ __launch_bounds__(256, 4)
void attn_mfma(const u16* __restrict__ Q, const u16* __restrict__ Km,
               const u16* __restrict__ Vt, u16* __restrict__ O) {
    __shared__ __align__(16) u16 Kt[2][64][36];
    __shared__ __align__(16) u16 Vl[2][32][68];
    int tid = threadIdx.x;
    int lane = tid & 63;
    int m = lane & 15, quad = lane >> 4;
    int w = tid >> 6;
    int bid = blockIdx.x;
    int qb = bid & 31;          // 32 q-blocks of 64 rows
    int bh = bid >> 5;          // b*8+h
    int b = bh >> 3, h = bh & 7;
    int q0 = qb * 64 + (w & 1) * 32;
    int hb = w >> 1;            // kv half: score tiles 2hb, 2hb+1
    size_t rowbase = (size_t)b * SEQ;

    bf16x8 qa0 = *(const bf16x8*)(Q + (rowbase + q0 + m) * D + h * DK + quad * 8);
    bf16x8 qa1 = *(const bf16x8*)(Q + (rowbase + q0 + 16 + m) * D + h * DK + quad * 8);

    const u16* kg = Km + rowbase * D + h * DK;
    const u16* vg = Vt + (size_t)bh * DK * SEQ;

    int krow = tid >> 2, kseg = tid & 3;
    int skv = (krow & 32) | (((krow >> 2) & 3) << 3) | (((krow >> 4) & 1) << 2) | (krow & 3);
    int vrow = tid >> 3, vseg = tid & 7;

    uint4 kreg = *(const uint4*)(kg + (size_t)skv * D + kseg * 8);
    uint4 vreg = *(const uint4*)(vg + (size_t)vrow * SEQ + vseg * 8);
    *(uint4*)(&Kt[0][krow][kseg * 8]) = kreg;
    *(uint4*)(&Vl[0][vrow][vseg * 8]) = vreg;

    f32x4 o0 = {0,0,0,0}, o1 = {0,0,0,0};   // q rows q0..q0+16
    f32x4 o2 = {0,0,0,0}, o3 = {0,0,0,0};   // q rows q0+16..q0+32
    float ls0 = 0.f, ls1 = 0.f;

    for (int i = 0; i < SEQ / 64; i++) {
        int buf = i & 1;
        if (i + 1 < SEQ / 64) {
            int kvn = (i + 1) * 64;
            kreg = *(const uint4*)(kg + (size_t)(kvn + skv) * D + kseg * 8);
            vreg = *(const uint4*)(vg + (size_t)vrow * SEQ + kvn + vseg * 8);
        }
        __syncthreads();
        f32x4 z = {0,0,0,0};
        bf16x8 kb0 = *(const bf16x8*)(&Kt[buf][(2 * hb) * 16 + m][quad * 8]);
        bf16x8 kb1 = *(const bf16x8*)(&Kt[buf][(2 * hb + 1) * 16 + m][quad * 8]);
        f32x4 s0 = MFMA16(kb0, qa0, z);
        f32x4 s1 = MFMA16(kb1, qa0, z);
        f32x4 s2 = MFMA16(kb0, qa1, z);
        f32x4 s3 = MFMA16(kb1, qa1, z);
        bf16x8 vb0 = *(const bf16x8*)(&Vl[buf][m][hb * 32 + quad * 8]);
        bf16x8 vb1 = *(const bf16x8*)(&Vl[buf][16 + m][hb * 32 + quad * 8]);
        {
            float pa0 = EXP2(s0[0]), pa1 = EXP2(s0[1]);
            float pa2 = EXP2(s0[2]), pa3 = EXP2(s0[3]);
            float pb0 = EXP2(s1[0]), pb1 = EXP2(s1[1]);
            float pb2 = EXP2(s1[2]), pb3 = EXP2(s1[3]);
            ls0 += ((pa0 + pa1) + (pa2 + pa3)) + ((pb0 + pb1) + (pb2 + pb3));
            uint4 pw;
            pw.x = pktrunc(pa0, pa1);
            pw.y = pktrunc(pa2, pa3);
            pw.z = pktrunc(pb0, pb1);
            pw.w = pktrunc(pb2, pb3);
            bf16x8 pf = __builtin_bit_cast(bf16x8, pw);
            o0 = MFMA16(pf, vb0, o0);
            o1 = MFMA16(pf, vb1, o1);
        }
        {
            float pa0 = EXP2(s2[0]), pa1 = EXP2(s2[1]);
            float pa2 = EXP2(s2[2]), pa3 = EXP2(s2[3]);
            float pb0 = EXP2(s3[0]), pb1 = EXP2(s3[1]);
            float pb2 = EXP2(s3[2]), pb3 = EXP2(s3[3]);
            ls1 += ((pa0 + pa1) + (pa2 + pa3)) + ((pb0 + pb1) + (pb2 + pb3));
            uint4 pw;
            pw.x = pktrunc(pa0, pa1);
            pw.y = pktrunc(pa2, pa3);
            pw.z = pktrunc(pb0, pb1);
            pw.w = pktrunc(pb2, pb3);
            bf16x8 pf = __builtin_bit_cast(bf16x8, pw);
            o2 = MFMA16(pf, vb0, o2);
            o3 = MFMA16(pf, vb1, o3);
        }
        if (i + 1 < SEQ / 64) {
            *(uint4*)(&Kt[buf ^ 1][krow][kseg * 8]) = kreg;
            *(uint4*)(&Vl[buf ^ 1][vrow][vseg * 8]) = vreg;
        }
    }
    // reduce ls across quads (q = m), then combine kv halves through LDS
    ls0 += __shfl_xor(ls0, 16); ls0 += __shfl_xor(ls0, 32);
    ls1 += __shfl_xor(ls1, 16); ls1 += __shfl_xor(ls1, 32);
    __syncthreads();                        // everyone done with Kt/Vl
    float* comb = (float*)&Kt[0][0][0];     // 2 slots x 64 lanes x 18 floats = 9216 B
    if (w >= 2) {
        float* c = comb + ((size_t)(w - 2) * 64 + lane) * 18;
#pragma unroll
        for (int r = 0; r < 4; r++) {
            c[r] = o0[r]; c[4 + r] = o1[r];
            c[8 + r] = o2[r]; c[12 + r] = o3[r];
        }
        c[16] = ls0; c[17] = ls1;
    }
    __syncthreads();
    if (w < 2) {
        const float* c = comb + ((size_t)w * 64 + lane) * 18;
#pragma unroll
        for (int r = 0; r < 4; r++) {
            o0[r] += c[r]; o1[r] += c[4 + r];
            o2[r] += c[8 + r]; o3[r] += c[12 + r];
        }
        ls0 += c[16]; ls1 += c[17];
        u16* ob0 = O + (rowbase + q0 + quad * 4) * D + h * DK;
        u16* ob1 = O + (rowbase + q0 + 16 + quad * 4) * D + h * DK;
#pragma unroll
        for (int r = 0; r < 4; r++) {
            float l0 = __shfl(ls0, quad * 4 + r);
            float l1 = __shfl(ls1, quad * 4 + r);
            float i0 = 1.f / l0, i1 = 1.f / l1;
            ob0[(size_t)r * D + m] = f2bf(o0[r] * i0);
            ob0[(size_t)r * D + 16 + m] = f2bf(o1[r] * i0);
            ob1[(size_t)r * D + m] = f2bf(o2[r] * i1);
            ob1[(size_t)r * D + 16 + m] = f2bf(o3[r] * i1);
        }
    }
}

// ---------- Wo GEMM + residual + LN -> f32 x1 + bf16 x1 (16-row blocks) ----------
__global__ __launch_bounds__(256, 2)
void wo_res_ln(const u16* __restrict__ A, const u16* __restrict__ Bt,
               const float* __restrict__ res, const float* __restrict__ g,
               const float* __restrict__ bb, float* __restrict__ outf,
               u16* __restrict__ outb) {
    __shared__ float Sy[4][16], Sq[4][16], Mu[16], Rs[16];
    int tid = threadIdx.x;
    int w = tid >> 6, lane = tid & 63;
    int m = lane & 15, quad = lane >> 4;
    int m0 = blockIdx.x << 4, n0 = w << 6;
    const u16* ap = A + (size_t)(m0 + m) * D + quad * 8;
    const u16* bp = Bt + (size_t)(n0 + m) * D + quad * 8;
    f32x4 acc[4] = {{0,0,0,0},{0,0,0,0},{0,0,0,0},{0,0,0,0}};
#pragma unroll
    for (int k0 = 0; k0 < D; k0 += 32) {
        bf16x8 a0 = *(const bf16x8*)(ap + k0);
#pragma unroll
        for (int t = 0; t < 4; t++)
            acc[t] = MFMA16(a0, *(const bf16x8*)(bp + (size_t)t * 16 * D + k0), acc[t]);
    }
#pragma unroll
    for (int r = 0; r < 4; r++) {
        int row = (quad << 2) + r;
        float sy = 0.f, sq = 0.f;
#pragma unroll
        for (int t = 0; t < 4; t++) {
            float y = acc[t][r] + res[(size_t)(m0 + row) * D + n0 + t * 16 + m];
            acc[t][r] = y;
            sy += y;
            sq += y * y;
        }
        sy += __shfl_xor(sy, 1); sq += __shfl_xor(sq, 1);
        sy += __shfl_xor(sy, 2); sq += __shfl_xor(sq, 2);
        sy += __shfl_xor(sy, 4); sq += __shfl_xor(sq, 4);
        sy += __shfl_xor(sy, 8); sq += __shfl_xor(sq, 8);
        if (m == 0) { Sy[w][row] = sy; Sq[w][row] = sq; }
    }
    __syncthreads();
    if (tid < 16) {
        float s = Sy[0][tid] + Sy[1][tid] + Sy[2][tid] + Sy[3][tid];
        float q = Sq[0][tid] + Sq[1][tid] + Sq[2][tid] + Sq[3][tid];
        float mu = s * (1.f / 256.f);
        float var = q * (1.f / 256.f) - mu * mu;
        Mu[tid] = mu;
        Rs[tid] = rsqrtf(var + LN_EPS);
    }
    __syncthreads();
#pragma unroll
    for (int r = 0; r < 4; r++) {
        int row = (quad << 2) + r;
        float mu = Mu[row], rs = Rs[row];
#pragma unroll
        for (int t = 0; t < 4; t++) {
            int col = n0 + t * 16 + m;
            float yv = (acc[t][r] - mu) * rs * g[col] + bb[col];
            outf[(size_t)(m0 + row) * D + col] = yv;
            outb[(size_t)(m0 + row) * D + col] = f2bf(yv);
        }
    }
}

// ---------- weight-stationary GLU: block owns 64 FF cols x 512 rows ----------
__global__ __launch_bounds__(512, 2)
void glu_ws(const u16* __restrict__ x1b, const u16* __restrict__ W1t,
            const u16* __restrict__ W2t, u16* __restrict__ G) {
    __shared__ __align__(16) u16 WL[2][64][260];
    int tid = threadIdx.x;
    int w = tid >> 6, lane = tid & 63;
    int m = lane & 15, quad = lane >> 4;
    int cg = blockIdx.x & 15, rg = blockIdx.x >> 4;
    int n0 = cg << 6;
#pragma unroll
    for (int i = 0; i < 4; i++) {
        int idx = i * 512 + tid;           // [0, 2048)
        int row = idx >> 5, seg = idx & 31;
        *(uint4*)(&WL[0][row][seg * 8]) =
            *(const uint4*)(W1t + (size_t)(n0 + row) * D + seg * 8);
        *(uint4*)(&WL[1][row][seg * 8]) =
            *(const uint4*)(W2t + (size_t)(n0 + row) * D + seg * 8);
    }
    __syncthreads();
    int mr = rg * 512 + w * 64;            // this wave's 64 rows
    f32x4 a1[4][4], a2[4][4];
#pragma unroll
    for (int u = 0; u < 4; u++)
#pragma unroll
        for (int t = 0; t < 4; t++) {
            a1[u][t] = (f32x4){0.f, 0.f, 0.f, 0.f};
            a2[u][t] = (f32x4){0.f, 0.f, 0.f, 0.f};
        }
#pragma unroll
    for (int k0 = 0; k0 < D; k0 += 32) {
        bf16x8 av[4];
#pragma unroll
        for (int u = 0; u < 4; u++)
            av[u] = *(const bf16x8*)(x1b + (size_t)(mr + u * 16 + m) * D + k0 + quad * 8);
#pragma unroll
        for (int t = 0; t < 4; t++) {
            bf16x8 w1 = *(const bf16x8*)(&WL[0][t * 16 + m][k0 + quad * 8]);
            bf16x8 w2 = *(const bf16x8*)(&WL[1][t * 16 + m][k0 + quad * 8]);
#pragma unroll
            for (int u = 0; u < 4; u++) {
                a1[u][t] = MFMA16(av[u], w1, a1[u][t]);
                a2[u][t] = MFMA16(av[u], w2, a2[u][t]);
            }
        }
    }
#pragma unroll
    for (int u = 0; u < 4; u++) {
        int row = mr + u * 16 + (quad << 2);
#pragma unroll
        for (int t = 0; t < 4; t++) {
            int col = n0 + t * 16 + m;
#pragma unroll
            for (int r = 0; r < 4; r++)
                G[(size_t)(row + r) * FF + col] = f2bf(silu_f(a1[u][t][r]) * a2[u][t][r]);
        }
    }
}

// ---------- Wout GEMM + residual + LN -> f32 d_out ----------
__global__ __launch_bounds__(1024, 4)
void wout_ln(const u16* __restrict__ G, const u16* __restrict__ Woutt,
             const float* __restrict__ x1f, const float* __restrict__ g,
             const float* __restrict__ bb, float* __restrict__ outf) {
    __shared__ __align__(16) u16 Gl[32][1044];
    __shared__ float Sy[16][32], Sq[16][32], Mu[32], Rs[32];
    int tid = threadIdx.x;
    int w = tid >> 6, lane = tid & 63;
    int m = lane & 15, quad = lane >> 4;
    int m0 = blockIdx.x << 5;
#pragma unroll
    for (int i = 0; i < 4; i++) {
        int idx = i * 1024 + tid;          // [0, 4096)
        int row = idx >> 7, seg = idx & 127;
        *(uint4*)(&Gl[row][seg * 8]) =
            *(const uint4*)(G + (size_t)(m0 + row) * FF + seg * 8);
    }
    __syncthreads();
    int n0p = w << 4;
    const u16* bp = Woutt + (size_t)(n0p + m) * FF + quad * 8;
    f32x4 acc[2] = {{0,0,0,0},{0,0,0,0}};
#pragma unroll 4
    for (int k0 = 0; k0 < FF; k0 += 32) {
        bf16x8 a0 = *(const bf16x8*)(&Gl[m][k0 + quad * 8]);
        bf16x8 a1v = *(const bf16x8*)(&Gl[16 + m][k0 + quad * 8]);
        bf16x8 bv = *(const bf16x8*)(bp + k0);
        acc[0] = MFMA16(a0, bv, acc[0]);
        acc[1] = MFMA16(a1v, bv, acc[1]);
    }
#pragma unroll
    for (int u = 0; u < 2; u++) {
#pragma unroll
        for (int r = 0; r < 4; r++) {
            int row = u * 16 + (quad << 2) + r;
            float y = acc[u][r] + x1f[(size_t)(m0 + row) * D + n0p + m];
            acc[u][r] = y;
            float sy = y, sq = y * y;
            sy += __shfl_xor(sy, 1); sq += __shfl_xor(sq, 1);
            sy += __shfl_xor(sy, 2); sq += __shfl_xor(sq, 2);
            sy += __shfl_xor(sy, 4); sq += __shfl_xor(sq, 4);
            sy += __shfl_xor(sy, 8); sq += __shfl_xor(sq, 8);
            if (m == 0) { Sy[w][row] = sy; Sq[w][row] = sq; }
        }
    }
    __syncthreads();
    if (tid < 32) {
        float s = 0.f, q = 0.f;
#pragma unroll
        for (int ww = 0; ww < 16; ww++) { s += Sy[ww][tid]; q += Sq[ww][tid]; }
        float mu = s * (1.f / 256.f);
        float var = q * (1.f / 256.f) - mu * mu;
        Mu[tid] = mu;
        Rs[tid] = rsqrtf(var + LN_EPS);
    }
    __syncthreads();
#pragma unroll
    for (int u = 0; u < 2; u++) {
#pragma unroll
        for (int r = 0; r < 4; r++) {
            int row = u * 16 + (quad << 2) + r;
            int col = n0p + m;
            outf[(size_t)(m0 + row) * D + col] =
                (acc[u][r] - Mu[row]) * Rs[row] * g[col] + bb[col];
        }
    }
}

// ---------- workspace layout (u16 element offsets), ~31.5 MiB ----------
#define WS_WQKVT  ((size_t)0)          // WqT|WkT|WvT|WoT, 65536 each
#define WS_WOT    ((size_t)196608)
#define WS_W1T    ((size_t)262144)
#define WS_W2T    ((size_t)524288)
#define WS_WOUTT  ((size_t)786432)
#define WS_Q      ((size_t)1048576)    // dead after attn
#define WS_K      ((size_t)3145728)    // dead after attn
#define WS_VT     ((size_t)5242880)    // dead after attn
#define WS_O      ((size_t)7340032)    // dead after wo_res_ln
#define WS_GATED  ((size_t)1048576)    // alias Q..O: exactly 8,388,608 elems
#define WS_X1F    ((size_t)9437184)    // f32 x1 (4,194,304 u16-equiv)
#define WS_X1B    ((size_t)13631488)   // bf16 x1 (2,097,152)
// end: 15,728,640 u16 = 31,457,280 bytes

extern "C" void kernel_launch(void* const* d_in, const int* in_sizes, int n_in,
                              void* d_out, int out_size, void* d_ws, size_t ws_size,
                              hipStream_t stream) {
    const float* x    = (const float*)d_in[0];
    const float* Wq   = (const float*)d_in[1];
    const float* Wk   = (const float*)d_in[2];
    const float* Wv   = (const float*)d_in[3];
    const float* Wo   = (const float*)d_in[4];
    const float* W1   = (const float*)d_in[5];
    const float* W2   = (const float*)d_in[6];
    const float* Wout = (const float*)d_in[7];
    const float* g1   = (const float*)d_in[8];
    const float* b1   = (const float*)d_in[9];
    const float* g2   = (const float*)d_in[10];
    const float* b2   = (const float*)d_in[11];

    u16* ws = (u16*)d_ws;
    float* x1f = (float*)(ws + WS_X1F);

    // 1. stage all weights (transposed bf16, Wq prescaled)
    stage_w<<<256, 256, 0, stream>>>(Wq, Wk, Wv, Wo, W1, W2, Wout, ws + WS_WQKVT);

    // 2. weight-stationary QKV projection from f32 x (V written transposed)
    gemm_qkv<<<768, 512, 0, stream>>>(x, ws + WS_WQKVT,
                                      ws + WS_Q, ws + WS_K, ws + WS_VT);

    // 3. MFMA flash attention (64 q-rows/block, kv-split waves, no spills)
    attn_mfma<<<1024, 256, 0, stream>>>(ws + WS_Q, ws + WS_K, ws + WS_VT, ws + WS_O);

    // 4. x1 = LN(x + O@Wo) -> f32 + bf16
    wo_res_ln<<<512, 256, 0, stream>>>(ws + WS_O, ws + WS_WOT, x, g1, b1,
                                       x1f, ws + WS_X1B);

    // 5. gated = silu(x1@W1)*(x1@W2)  (weight-stationary, 64 KB LDS weights)
    glu_ws<<<256, 512, 0, stream>>>(ws + WS_X1B, ws + WS_W1T, ws + WS_W2T,
                                    ws + WS_GATED);

    // 6. out = LN(x1 + gated@Wout) -> f32 d_out (gated tile fully in LDS)
    wout_ln<<<256, 1024, 0, stream>>>(ws + WS_GATED, ws + WS_WOUTT, x1f,
                                      g2, b2, (float*)d_out);
}

// Round 27
// 175.442 us; speedup vs baseline: 1.1352x; 1.0154x over previous
//
#include <hip/hip_runtime.h>

#define D 256
#define H 8
#define DK 32
#define FF 1024
#define SEQ 2048
#define BATCH 4
#define MROWS (BATCH * SEQ)   // 8192
#define LN_EPS 1e-5f
#define QSCALE (0.1767766952966369f * 1.4426950408889634f)  // attn scale * log2(e)
#define LOG2E 1.4426950408889634f

typedef unsigned short u16;
typedef unsigned int u32;
typedef __attribute__((ext_vector_type(8))) short bf16x8;
typedef __attribute__((ext_vector_type(4))) float f32x4;

#define MFMA16(a, b, c) __builtin_amdgcn_mfma_f32_16x16x32_bf16(a, b, c, 0, 0, 0)

#if __has_builtin(__builtin_amdgcn_exp2f)
#define EXP2(x) __builtin_amdgcn_exp2f(x)
#else
#define EXP2(x) exp2f(x)
#endif
#if __has_builtin(__builtin_amdgcn_rcpf)
#define RCPF(x) __builtin_amdgcn_rcpf(x)
#else
#define RCPF(x) (1.f / (x))
#endif

// ---------- bf16 helpers ----------
__device__ __forceinline__ u16 f2bf(float f) {
    union { float f; u32 u; } x; x.f = f;
    u32 r = x.u + 0x7fffu + ((x.u >> 16) & 1u);  // RNE
    return (u16)(r >> 16);
}
__device__ __forceinline__ u32 pack2(float a, float b) {
    return (u32)f2bf(a) | ((u32)f2bf(b) << 16);
}
__device__ __forceinline__ u32 pktrunc(float a, float b) {
    u32 ua = __builtin_bit_cast(u32, a), ub = __builtin_bit_cast(u32, b);
    return __builtin_amdgcn_perm(ub, ua, 0x07060302u);
}
__device__ __forceinline__ float silu_f(float x) {
    return x * RCPF(1.f + EXP2(-x * LOG2E));
}

// ---------- stage all 7 weights: f32 [K,N] -> bf16 [N,K], LDS-tiled ----------
__global__ void stage_w(const float* __restrict__ Wq, const float* __restrict__ Wk,
                        const float* __restrict__ Wv, const float* __restrict__ Wo,
                        const float* __restrict__ W1, const float* __restrict__ W2,
                        const float* __restrict__ Wout, u16* __restrict__ dst) {
    __shared__ float T[64][65];
    int bid = blockIdx.x, tid = threadIdx.x;
    const float* src;
    size_t dbase;
    int K, N, tile;
    float sc = 1.f;
    if (bid < 64) {
        int which = bid >> 4;
        tile = bid & 15;
        src = which == 0 ? Wq : which == 1 ? Wk : which == 2 ? Wv : Wo;
        if (which == 0) sc = QSCALE;
        dbase = (size_t)which << 16;
        K = 256; N = 256;
    } else if (bid < 192) {
        int which = (bid - 64) >> 6;
        tile = (bid - 64) & 63;
        src = which ? W2 : W1;
        dbase = 262144 + (size_t)which * 262144;
        K = 256; N = 1024;
    } else {
        tile = bid - 192;
        src = Wout;
        dbase = 786432;
        K = 1024; N = 256;
    }
    int ntn = N >> 6;
    int k0 = (tile / ntn) << 6, n0 = (tile % ntn) << 6;
#pragma unroll
    for (int p = 0; p < 4; p++) {
        int r = p * 16 + (tid >> 4), c = (tid & 15) * 4;
        float4 v = *(const float4*)(src + (size_t)(k0 + r) * N + n0 + c);
        T[c + 0][r] = v.x * sc;
        T[c + 1][r] = v.y * sc;
        T[c + 2][r] = v.z * sc;
        T[c + 3][r] = v.w * sc;
    }
    __syncthreads();
#pragma unroll
    for (int p = 0; p < 4; p++) {
        int n = p * 16 + (tid >> 4), k = (tid & 15) * 4;
        uint2 o;
        o.x = pack2(T[n][k], T[n][k + 1]);
        o.y = pack2(T[n][k + 2], T[n][k + 3]);
        *(uint2*)(dst + dbase + (size_t)(n0 + n) * K + k0 + k) = o;
    }
}

// ---------- weight-stationary QKV GEMM, 128-col groups ----------
// 384 blocks (6 col-groups x 64 row-groups) x 512 threads (8 waves).
// Block stages its 128x256 weight slice (66 KB LDS, 2 blocks/CU); x read 6x
// instead of 12x. Wave = 16 rows x 128 cols. cg>>1: 0->Q, 1->K, 2->V
// (V written transposed as Vt[bh*32+dk][s]).
__global__ __launch_bounds__(512, 2)
void gemm_qkv(const float* __restrict__ X, const u16* __restrict__ Bt,
              u16* __restrict__ Qo, u16* __restrict__ Ko,
              u16* __restrict__ Vo) {
    __shared__ __align__(16) u16 WL[128][264];
    int tid = threadIdx.x;
    int w = tid >> 6, lane = tid & 63;
    int m = lane & 15, quad = lane >> 4;
    int cg = blockIdx.x % 6, rg = blockIdx.x / 6;
    int n0 = cg << 7;
    // stage weights: 128 rows x 32 segs of 16B = 4096 uint4; 8 per thread
#pragma unroll
    for (int i = 0; i < 8; i++) {
        int idx = i * 512 + tid;
        int row = idx >> 5, seg = idx & 31;
        *(uint4*)(&WL[row][seg * 8]) =
            *(const uint4*)(Bt + (size_t)(n0 + row) * D + seg * 8);
    }
    __syncthreads();
    int m0 = rg * 128 + w * 16;            // this wave's 16 rows
    const float* xp = X + (size_t)(m0 + m) * D + quad * 8;
    f32x4 acc[8];
#pragma unroll
    for (int t = 0; t < 8; t++) acc[t] = (f32x4){0.f, 0.f, 0.f, 0.f};
#pragma unroll
    for (int k0 = 0; k0 < D; k0 += 32) {
        float4 f0 = *(const float4*)(xp + k0);
        float4 f1 = *(const float4*)(xp + k0 + 4);
        uint4 u0;
        u0.x = pktrunc(f0.x, f0.y); u0.y = pktrunc(f0.z, f0.w);
        u0.z = pktrunc(f1.x, f1.y); u0.w = pktrunc(f1.z, f1.w);
        bf16x8 a0 = __builtin_bit_cast(bf16x8, u0);
#pragma unroll
        for (int t = 0; t < 8; t++) {
            bf16x8 bv = *(const bf16x8*)(&WL[t * 16 + m][k0 + quad * 8]);
            acc[t] = MFMA16(a0, bv, acc[t]);
        }
    }
    int seg = cg >> 1;
    int nc0 = (cg & 1) << 7;
    int row = m0 + (quad << 2);
    if (seg < 2) {
        u16* out = seg ? Ko : Qo;
#pragma unroll
        for (int t = 0; t < 8; t++) {
            int col = nc0 + t * 16 + m;
#pragma unroll
            for (int r = 0; r < 4; r++)
                out[(size_t)(row + r) * D + col] = f2bf(acc[t][r]);
        }
    } else {
        int b = row >> 11, sl = row & 2047;
#pragma unroll
        for (int t = 0; t < 8; t++) {
            int col = nc0 + t * 16 + m;          // d in [0,256)
            int hh = col >> 5, dk = col & 31;
            size_t base = ((size_t)(b * 8 + hh) * 32 + dk) * SEQ + sl;
            uint2 pk;
            pk.x = pack2(acc[t][0], acc[t][1]);
            pk.y = pack2(acc[t][2], acc[t][3]);
            *(uint2*)(Vo + base) = pk;
        }
    }
}

// ---------- MFMA flash attention: 64 q-rows/block, kv-split waves (R26) ----
__global__ __launch_bounds__(256, 4)
void attn_mfma(const u16* __restrict__ Q, const u16* __restrict__ Km,
               const u16* __restrict__ Vt, u16* __restrict__ O) {
    __shared__ __align__(16) u16 Kt[2][64][36];
    __shared__ __align__(16) u16 Vl[2][32][68];
    int tid = threadIdx.x;
    int lane = tid & 63;
    int m = lane & 15, quad = lane >> 4;
    int w = tid >> 6;
    int bid = blockIdx.x;
    int qb = bid & 31;          // 32 q-blocks of 64 rows
    int bh = bid >> 5;          // b*8+h
    int b = bh >> 3, h = bh & 7;
    int q0 = qb * 64 + (w & 1) * 32;
    int hb = w >> 1;            // kv half: score tiles 2hb, 2hb+1
    size_t rowbase = (size_t)b * SEQ;

    bf16x8 qa0 = *(const bf16x8*)(Q + (rowbase + q0 + m) * D + h * DK + quad * 8);
    bf16x8 qa1 = *(const bf16x8*)(Q + (rowbase + q0 + 16 + m) * D + h * DK + quad * 8);

    const u16* kg = Km + rowbase * D + h * DK;
    const u16* vg = Vt + (size_t)bh * DK * SEQ;

    int krow = tid >> 2, kseg = tid & 3;
    int skv = (krow & 32) | (((krow >> 2) & 3) << 3) | (((krow >> 4) & 1) << 2) | (krow & 3);
    int vrow = tid >> 3, vseg = tid & 7;

    uint4 kreg = *(const uint4*)(kg + (size_t)skv * D + kseg * 8);
    uint4 vreg = *(const uint4*)(vg + (size_t)vrow * SEQ + vseg * 8);
    *(uint4*)(&Kt[0][krow][kseg * 8]) = kreg;
    *(uint4*)(&Vl[0][vrow][vseg * 8]) = vreg;

    f32x4 o0 = {0,0,0,0}, o1 = {0,0,0,0};   // q rows q0..q0+16
    f32x4 o2 = {0,0,0,0}, o3 = {0,0,0,0};   // q rows q0+16..q0+32
    float ls0 = 0.f, ls1 = 0.f;

    for (int i = 0; i < SEQ / 64; i++) {
        int buf = i & 1;
        if (i + 1 < SEQ / 64) {
            int kvn = (i + 1) * 64;
            kreg = *(const uint4*)(kg + (size_t)(kvn + skv) * D + kseg * 8);
            vreg = *(const uint4*)(vg + (size_t)vrow * SEQ + kvn + vseg * 8);
        }
        __syncthreads();
        f32x4 z = {0,0,0,0};
        bf16x8 kb0 = *(const bf16x8*)(&Kt[buf][(2 * hb) * 16 + m][quad * 8]);
        bf16x8 kb1 = *(const bf16x8*)(&Kt[buf][(2 * hb + 1) * 16 + m][quad * 8]);
        f32x4 s0 = MFMA16(kb0, qa0, z);
        f32x4 s1 = MFMA16(kb1, qa0, z);
        f32x4 s2 = MFMA16(kb0, qa1, z);
        f32x4 s3 = MFMA16(kb1, qa1, z);
        bf16x8 vb0 = *(const bf16x8*)(&Vl[buf][m][hb * 32 + quad * 8]);
        bf16x8 vb1 = *(const bf16x8*)(&Vl[buf][16 + m][hb * 32 + quad * 8]);
        {
            float pa0 = EXP2(s0[0]), pa1 = EXP2(s0[1]);
            float pa2 = EXP2(s0[2]), pa3 = EXP2(s0[3]);
            float pb0 = EXP2(s1[0]), pb1 = EXP2(s1[1]);
            float pb2 = EXP2(s1[2]), pb3 = EXP2(s1[3]);
            ls0 += ((pa0 + pa1) + (pa2 + pa3)) + ((pb0 + pb1) + (pb2 + pb3));
            uint4 pw;
            pw.x = pktrunc(pa0, pa1);
            pw.y = pktrunc(pa2, pa3);
            pw.z = pktrunc(pb0, pb1);
            pw.w = pktrunc(pb2, pb3);
            bf16x8 pf = __builtin_bit_cast(bf16x8, pw);
            o0 = MFMA16(pf, vb0, o0);
            o1 = MFMA16(pf, vb1, o1);
        }
        {
            float pa0 = EXP2(s2[0]), pa1 = EXP2(s2[1]);
            float pa2 = EXP2(s2[2]), pa3 = EXP2(s2[3]);
            float pb0 = EXP2(s3[0]), pb1 = EXP2(s3[1]);
            float pb2 = EXP2(s3[2]), pb3 = EXP2(s3[3]);
            ls1 += ((pa0 + pa1) + (pa2 + pa3)) + ((pb0 + pb1) + (pb2 + pb3));
            uint4 pw;
            pw.x = pktrunc(pa0, pa1);
            pw.y = pktrunc(pa2, pa3);
            pw.z = pktrunc(pb0, pb1);
            pw.w = pktrunc(pb2, pb3);
            bf16x8 pf = __builtin_bit_cast(bf16x8, pw);
            o2 = MFMA16(pf, vb0, o2);
            o3 = MFMA16(pf, vb1, o3);
        }
        if (i + 1 < SEQ / 64) {
            *(uint4*)(&Kt[buf ^ 1][krow][kseg * 8]) = kreg;
            *(uint4*)(&Vl[buf ^ 1][vrow][vseg * 8]) = vreg;
        }
    }
    // reduce ls across quads (q = m), then combine kv halves through LDS
    ls0 += __shfl_xor(ls0, 16); ls0 += __shfl_xor(ls0, 32);
    ls1 += __shfl_xor(ls1, 16); ls1 += __shfl_xor(ls1, 32);
    __syncthreads();                        // everyone done with Kt/Vl
    float* comb = (float*)&Kt[0][0][0];     // 2 slots x 64 lanes x 18 floats = 9216 B
    if (w >= 2) {
        float* c = comb + ((size_t)(w - 2) * 64 + lane) * 18;
#pragma unroll
        for (int r = 0; r < 4; r++) {
            c[r] = o0[r]; c[4 + r] = o1[r];
            c[8 + r] = o2[r]; c[12 + r] = o3[r];
        }
        c[16] = ls0; c[17] = ls1;
    }
    __syncthreads();
    if (w < 2) {
        const float* c = comb + ((size_t)w * 64 + lane) * 18;
#pragma unroll
        for (int r = 0; r < 4; r++) {
            o0[r] += c[r]; o1[r] += c[4 + r];
            o2[r] += c[8 + r]; o3[r] += c[12 + r];
        }
        ls0 += c[16]; ls1 += c[17];
        u16* ob0 = O + (rowbase + q0 + quad * 4) * D + h * DK;
        u16* ob1 = O + (rowbase + q0 + 16 + quad * 4) * D + h * DK;
#pragma unroll
        for (int r = 0; r < 4; r++) {
            float l0 = __shfl(ls0, quad * 4 + r);
            float l1 = __shfl(ls1, quad * 4 + r);
            float i0 = 1.f / l0, i1 = 1.f / l1;
            ob0[(size_t)r * D + m] = f2bf(o0[r] * i0);
            ob0[(size_t)r * D + 16 + m] = f2bf(o1[r] * i0);
            ob1[(size_t)r * D + m] = f2bf(o2[r] * i1);
            ob1[(size_t)r * D + 16 + m] = f2bf(o3[r] * i1);
        }
    }
}

// ---------- Wo GEMM + residual + LN -> f32 x1 + bf16 x1 (16-row blocks) ----------
__global__ __launch_bounds__(256, 2)
void wo_res_ln(const u16* __restrict__ A, const u16* __restrict__ Bt,
               const float* __restrict__ res, const float* __restrict__ g,
               const float* __restrict__ bb, float* __restrict__ outf,
               u16* __restrict__ outb) {
    __shared__ float Sy[4][16], Sq[4][16], Mu[16], Rs[16];
    int tid = threadIdx.x;
    int w = tid >> 6, lane = tid & 63;
    int m = lane & 15, quad = lane >> 4;
    int m0 = blockIdx.x << 4, n0 = w << 6;
    const u16* ap = A + (size_t)(m0 + m) * D + quad * 8;
    const u16* bp = Bt + (size_t)(n0 + m) * D + quad * 8;
    f32x4 acc[4] = {{0,0,0,0},{0,0,0,0},{0,0,0,0},{0,0,0,0}};
#pragma unroll
    for (int k0 = 0; k0 < D; k0 += 32) {
        bf16x8 a0 = *(const bf16x8*)(ap + k0);
#pragma unroll
        for (int t = 0; t < 4; t++)
            acc[t] = MFMA16(a0, *(const bf16x8*)(bp + (size_t)t * 16 * D + k0), acc[t]);
    }
#pragma unroll
    for (int r = 0; r < 4; r++) {
        int row = (quad << 2) + r;
        float sy = 0.f, sq = 0.f;
#pragma unroll
        for (int t = 0; t < 4; t++) {
            float y = acc[t][r] + res[(size_t)(m0 + row) * D + n0 + t * 16 + m];
            acc[t][r] = y;
            sy += y;
            sq += y * y;
        }
        sy += __shfl_xor(sy, 1); sq += __shfl_xor(sq, 1);
        sy += __shfl_xor(sy, 2); sq += __shfl_xor(sq, 2);
        sy += __shfl_xor(sy, 4); sq += __shfl_xor(sq, 4);
        sy += __shfl_xor(sy, 8); sq += __shfl_xor(sq, 8);
        if (m == 0) { Sy[w][row] = sy; Sq[w][row] = sq; }
    }
    __syncthreads();
    if (tid < 16) {
        float s = Sy[0][tid] + Sy[1][tid] + Sy[2][tid] + Sy[3][tid];
        float q = Sq[0][tid] + Sq[1][tid] + Sq[2][tid] + Sq[3][tid];
        float mu = s * (1.f / 256.f);
        float var = q * (1.f / 256.f) - mu * mu;
        Mu[tid] = mu;
        Rs[tid] = rsqrtf(var + LN_EPS);
    }
    __syncthreads();
#pragma unroll
    for (int r = 0; r < 4; r++) {
        int row = (quad << 2) + r;
        float mu = Mu[row], rs = Rs[row];
#pragma unroll
        for (int t = 0; t < 4; t++) {
            int col = n0 + t * 16 + m;
            float yv = (acc[t][r] - mu) * rs * g[col] + bb[col];
            outf[(size_t)(m0 + row) * D + col] = yv;
            outb[(size_t)(m0 + row) * D + col] = f2bf(yv);
        }
    }
}

// ---------- weight-stationary GLU: block owns 64 FF cols x 512 rows ----------
__global__ __launch_bounds__(512, 2)
void glu_ws(const u16* __restrict__ x1b, const u16* __restrict__ W1t,
            const u16* __restrict__ W2t, u16* __restrict__ G) {
    __shared__ __align__(16) u16 WL[2][64][260];
    int tid = threadIdx.x;
    int w = tid >> 6, lane = tid & 63;
    int m = lane & 15, quad = lane >> 4;
    int cg = blockIdx.x & 15, rg = blockIdx.x >> 4;
    int n0 = cg << 6;
#pragma unroll
    for (int i = 0; i < 4; i++) {
        int idx = i * 512 + tid;           // [0, 2048)
        int row = idx >> 5, seg = idx & 31;
        *(uint4*)(&WL[0][row][seg * 8]) =
            *(const uint4*)(W1t + (size_t)(n0 + row) * D + seg * 8);
        *(uint4*)(&WL[1][row][seg * 8]) =
            *(const uint4*)(W2t + (size_t)(n0 + row) * D + seg * 8);
    }
    __syncthreads();
    int mr = rg * 512 + w * 64;            // this wave's 64 rows
    f32x4 a1[4][4], a2[4][4];
#pragma unroll
    for (int u = 0; u < 4; u++)
#pragma unroll
        for (int t = 0; t < 4; t++) {
            a1[u][t] = (f32x4){0.f, 0.f, 0.f, 0.f};
            a2[u][t] = (f32x4){0.f, 0.f, 0.f, 0.f};
        }
#pragma unroll
    for (int k0 = 0; k0 < D; k0 += 32) {
        bf16x8 av[4];
#pragma unroll
        for (int u = 0; u < 4; u++)
            av[u] = *(const bf16x8*)(x1b + (size_t)(mr + u * 16 + m) * D + k0 + quad * 8);
#pragma unroll
        for (int t = 0; t < 4; t++) {
            bf16x8 w1 = *(const bf16x8*)(&WL[0][t * 16 + m][k0 + quad * 8]);
            bf16x8 w2 = *(const bf16x8*)(&WL[1][t * 16 + m][k0 + quad * 8]);
#pragma unroll
            for (int u = 0; u < 4; u++) {
                a1[u][t] = MFMA16(av[u], w1, a1[u][t]);
                a2[u][t] = MFMA16(av[u], w2, a2[u][t]);
            }
        }
    }
#pragma unroll
    for (int u = 0; u < 4; u++) {
        int row = mr + u * 16 + (quad << 2);
#pragma unroll
        for (int t = 0; t < 4; t++) {
            int col = n0 + t * 16 + m;
#pragma unroll
            for (int r = 0; r < 4; r++)
                G[(size_t)(row + r) * FF + col] = f2bf(silu_f(a1[u][t][r]) * a2[u][t][r]);
        }
    }
}

// ---------- Wout GEMM + residual + LN -> f32 d_out ----------
__global__ __launch_bounds__(1024, 4)
void wout_ln(const u16* __restrict__ G, const u16* __restrict__ Woutt,
             const float* __restrict__ x1f, const float* __restrict__ g,
             const float* __restrict__ bb, float* __restrict__ outf) {
    __shared__ __align__(16) u16 Gl[32][1044];
    __shared__ float Sy[16][32], Sq[16][32], Mu[32], Rs[32];
    int tid = threadIdx.x;
    int w = tid >> 6, lane = tid & 63;
    int m = lane & 15, quad = lane >> 4;
    int m0 = blockIdx.x << 5;
#pragma unroll
    for (int i = 0; i < 4; i++) {
        int idx = i * 1024 + tid;          // [0, 4096)
        int row = idx >> 7, seg = idx & 127;
        *(uint4*)(&Gl[row][seg * 8]) =
            *(const uint4*)(G + (size_t)(m0 + row) * FF + seg * 8);
    }
    __syncthreads();
    int n0p = w << 4;
    const u16* bp = Woutt + (size_t)(n0p + m) * FF + quad * 8;
    f32x4 acc[2] = {{0,0,0,0},{0,0,0,0}};
#pragma unroll 4
    for (int k0 = 0; k0 < FF; k0 += 32) {
        bf16x8 a0 = *(const bf16x8*)(&Gl[m][k0 + quad * 8]);
        bf16x8 a1v = *(const bf16x8*)(&Gl[16 + m][k0 + quad * 8]);
        bf16x8 bv = *(const bf16x8*)(bp + k0);
        acc[0] = MFMA16(a0, bv, acc[0]);
        acc[1] = MFMA16(a1v, bv, acc[1]);
    }
#pragma unroll
    for (int u = 0; u < 2; u++) {
#pragma unroll
        for (int r = 0; r < 4; r++) {
            int row = u * 16 + (quad << 2) + r;
            float y = acc[u][r] + x1f[(size_t)(m0 + row) * D + n0p + m];
            acc[u][r] = y;
            float sy = y, sq = y * y;
            sy += __shfl_xor(sy, 1); sq += __shfl_xor(sq, 1);
            sy += __shfl_xor(sy, 2); sq += __shfl_xor(sq, 2);
            sy += __shfl_xor(sy, 4); sq += __shfl_xor(sq, 4);
            sy += __shfl_xor(sy, 8); sq += __shfl_xor(sq, 8);
            if (m == 0) { Sy[w][row] = sy; Sq[w][row] = sq; }
        }
    }
    __syncthreads();
    if (tid < 32) {
        float s = 0.f, q = 0.f;
#pragma unroll
        for (int ww = 0; ww < 16; ww++) { s += Sy[ww][tid]; q += Sq[ww][tid]; }
        float mu = s * (1.f / 256.f);
        float var = q * (1.f / 256.f) - mu * mu;
        Mu[tid] = mu;
        Rs[tid] = rsqrtf(var + LN_EPS);
    }
    __syncthreads();
#pragma unroll
    for (int u = 0; u < 2; u++) {
#pragma unroll
        for (int r = 0; r < 4; r++) {
            int row = u * 16 + (quad << 2) + r;
            int col = n0p + m;
            outf[(size_t)(m0 + row) * D + col] =
                (acc[u][r] - Mu[row]) * Rs[row] * g[col] + bb[col];
        }
    }
}

// ---------- workspace layout (u16 element offsets), ~31.5 MiB ----------
#define WS_WQKVT  ((size_t)0)          // WqT|WkT|WvT|WoT, 65536 each
#define WS_WOT    ((size_t)196608)
#define WS_W1T    ((size_t)262144)
#define WS_W2T    ((size_t)524288)
#define WS_WOUTT  ((size_t)786432)
#define WS_Q      ((size_t)1048576)    // dead after attn
#define WS_K      ((size_t)3145728)    // dead after attn
#define WS_VT     ((size_t)5242880)    // dead after attn
#define WS_O      ((size_t)7340032)    // dead after wo_res_ln
#define WS_GATED  ((size_t)1048576)    // alias Q..O: exactly 8,388,608 elems
#define WS_X1F    ((size_t)9437184)    // f32 x1 (4,194,304 u16-equiv)
#define WS_X1B    ((size_t)13631488)   // bf16 x1 (2,097,152)
// end: 15,728,640 u16 = 31,457,280 bytes

extern "C" void kernel_launch(void* const* d_in, const int* in_sizes, int n_in,
                              void* d_out, int out_size, void* d_ws, size_t ws_size,
                              hipStream_t stream) {
    const float* x    = (const float*)d_in[0];
    const float* Wq   = (const float*)d_in[1];
    const float* Wk   = (const float*)d_in[2];
    const float* Wv   = (const float*)d_in[3];
    const float* Wo   = (const float*)d_in[4];
    const float* W1   = (const float*)d_in[5];
    const float* W2   = (const float*)d_in[6];
    const float* Wout = (const float*)d_in[7];
    const float* g1   = (const float*)d_in[8];
    const float* b1   = (const float*)d_in[9];
    const float* g2   = (const float*)d_in[10];
    const float* b2   = (const float*)d_in[11];

    u16* ws = (u16*)d_ws;
    float* x1f = (float*)(ws + WS_X1F);

    // 1. stage all weights (transposed bf16, Wq prescaled)
    stage_w<<<256, 256, 0, stream>>>(Wq, Wk, Wv, Wo, W1, W2, Wout, ws + WS_WQKVT);

    // 2. weight-stationary QKV projection, 128-col groups (x read 6x not 12x)
    gemm_qkv<<<384, 512, 0, stream>>>(x, ws + WS_WQKVT,
                                      ws + WS_Q, ws + WS_K, ws + WS_VT);

    // 3. MFMA flash attention (64 q-rows/block, kv-split waves, no spills)
    attn_mfma<<<1024, 256, 0, stream>>>(ws + WS_Q, ws + WS_K, ws + WS_VT, ws + WS_O);

    // 4. x1 = LN(x + O@Wo) -> f32 + bf16
    wo_res_ln<<<512, 256, 0, stream>>>(ws + WS_O, ws + WS_WOT, x, g1, b1,
                                       x1f, ws + WS_X1B);

    // 5. gated = silu(x1@W1)*(x1@W2)  (weight-stationary, 64 KB LDS weights)
    glu_ws<<<256, 512, 0, stream>>>(ws + WS_X1B, ws + WS_W1T, ws + WS_W2T,
                                    ws + WS_GATED);

    // 6. out = LN(x1 + gated@Wout) -> f32 d_out (gated tile fully in LDS)
    wout_ln<<<256, 1024, 0, stream>>>(ws + WS_GATED, ws + WS_WOUTT, x1f,
                                      g2, b2, (float*)d_out);
}